// Round 1
// baseline (25248.341 us; speedup 1.0000x reference)
//
#include <hip/hip_runtime.h>
#include <cmath>

// Problem dims (fixed by the reference)
constexpr int kB = 32, kH = 48, kT = 24, kS = 256, kA = 64, kR = 8, kF = 1024;
constexpr int kSEQ = kH + 1;           // 49 = history + present step
constexpr float kEPS = 1e-5f;

// Persistent-kernel config
constexpr int G  = 256;                // grid blocks (<= 256 CUs -> co-resident)
constexpr int BT = 512;                // threads per block (8 waves)
constexpr int FT = kF / G;             // 4 hidden columns per block

__device__ __forceinline__ float gelu_f(float x) {
  return 0.5f * x * (1.0f + erff(x * 0.7071067811865476f));
}
__device__ __forceinline__ float sigmoid_f(float x) {
  return 1.0f / (1.0f + expf(-x));
}

// ---------------- grid-wide barrier --------------------------------------
// flags[G]: per-block arrival generation (distinct cache lines -> no atomic
// serialization). Block 0 aggregates, then publishes `go`. AGENT-scope
// release/acquire for cross-XCD visibility (per-XCD L2 non-coherent).
__device__ __forceinline__ void grid_barrier(int* flags, int* go, int& gen) {
  __syncthreads();                       // also drains vmcnt (data stores at L2)
  if (threadIdx.x == 0) {
    __threadfence();                     // push dirty L2 lines to LLC
    __hip_atomic_store(&flags[blockIdx.x], gen, __ATOMIC_RELEASE, __HIP_MEMORY_SCOPE_AGENT);
  }
  if (blockIdx.x == 0) {
    if (threadIdx.x < G) {
      while (__hip_atomic_load(&flags[threadIdx.x], __ATOMIC_ACQUIRE, __HIP_MEMORY_SCOPE_AGENT) < gen) {
        __builtin_amdgcn_s_sleep(1);
      }
    }
    __syncthreads();
    if (threadIdx.x == 0) {
      __hip_atomic_store(go, gen, __ATOMIC_RELEASE, __HIP_MEMORY_SCOPE_AGENT);
    }
  }
  if (threadIdx.x == 0) {
    while (__hip_atomic_load(go, __ATOMIC_ACQUIRE, __HIP_MEMORY_SCOPE_AGENT) < gen) {
      __builtin_amdgcn_s_sleep(1);
    }
  }
  __syncthreads();                       // acquire-inv ordered before data reads
  gen++;
}

// ---------------- one GRU layer step (per block: FT columns, all batch) ----
// thread = (kh, half, o): kh splits K in two, half selects Wi*x vs Wh*h,
// o = (b<<2)|fi indexes the block's 32x4 output tile. Partials meet in LDS.
#define PART(kh, half, gate) (((((kh)*2 + (half))*3) + (gate)) * 128)

__device__ __forceinline__ void layer_step(
    const float* __restrict__ x, const float* __restrict__ hcur, float* __restrict__ hnxt,
    const float* __restrict__ Wi, const float* __restrict__ Wh,
    const float* __restrict__ bi, const float* __restrict__ bh,
    float* smem)
{
  const int tid  = threadIdx.x;
  const int o    = tid & 127;
  const int half = (tid >> 7) & 1;
  const int kh   = tid >> 8;
  const int b    = o >> 2;
  const int fi   = o & 3;
  const int f    = blockIdx.x * FT + fi;

  const float* src = (half ? hcur : x) + (size_t)b * kF + kh * (kF / 2);
  const float* W   = half ? Wh : Wi;
  const float* r0p = W + (size_t)f          * kF + kh * (kF / 2);
  const float* r1p = W + (size_t)(kF  + f)  * kF + kh * (kF / 2);
  const float* r2p = W + (size_t)(2*kF + f) * kF + kh * (kF / 2);

  float ar = 0.f, az = 0.f, an = 0.f;
  #pragma unroll 8
  for (int k = 0; k < kF / 2; k += 4) {
    float4 xv = *(const float4*)(src + k);
    float4 w0 = *(const float4*)(r0p + k);
    float4 w1 = *(const float4*)(r1p + k);
    float4 w2 = *(const float4*)(r2p + k);
    ar += xv.x*w0.x + xv.y*w0.y + xv.z*w0.z + xv.w*w0.w;
    az += xv.x*w1.x + xv.y*w1.y + xv.z*w1.z + xv.w*w1.w;
    an += xv.x*w2.x + xv.y*w2.y + xv.z*w2.z + xv.w*w2.w;
  }
  smem[PART(kh, half, 0) + o] = ar;
  smem[PART(kh, half, 1) + o] = az;
  smem[PART(kh, half, 2) + o] = an;
  __syncthreads();
  if (tid < 128) {
    float gir = smem[PART(0,0,0)+o] + smem[PART(1,0,0)+o] + bi[f];
    float giz = smem[PART(0,0,1)+o] + smem[PART(1,0,1)+o] + bi[kF + f];
    float gin = smem[PART(0,0,2)+o] + smem[PART(1,0,2)+o] + bi[2*kF + f];
    float ghr = smem[PART(0,1,0)+o] + smem[PART(1,1,0)+o] + bh[f];
    float ghz = smem[PART(0,1,1)+o] + smem[PART(1,1,1)+o] + bh[kF + f];
    float ghn = smem[PART(0,1,2)+o] + smem[PART(1,1,2)+o] + bh[2*kF + f];
    float r = sigmoid_f(gir + ghr);
    float z = sigmoid_f(giz + ghz);
    float n = tanhf(gin + r * ghn);
    float hold = hcur[(size_t)b * kF + f];
    hnxt[(size_t)b * kF + f] = (1.f - z) * n + z * hold;
  }
}

// ---------------- head: r = tanh(y@Wr^T+br), s = y@Ws^T+bs -----------------
__device__ __forceinline__ void head_rs(
    const float* __restrict__ y,
    const float* __restrict__ W_sout, const float* __restrict__ b_sout,
    const float* __restrict__ W_reward, const float* __restrict__ b_reward,
    float* __restrict__ out_r, float* __restrict__ out_s, float* __restrict__ s_scr,
    int t, float* smem)
{
  if (blockIdx.x < kB) {
    const int b = blockIdx.x;
    const int tid = threadIdx.x;
    float* yrow = smem;                                    // kF floats
    for (int i = tid; i < kF; i += BT) yrow[i] = y[(size_t)b * kF + i];
    __syncthreads();
    if (tid < kS) {
      const float* wr = W_sout + (size_t)tid * kF;
      float acc = b_sout[tid];
      for (int k = 0; k < kF; k += 4) {
        float4 w  = *(const float4*)(wr + k);
        float4 yv = *(const float4*)(yrow + k);
        acc += yv.x*w.x + yv.y*w.y + yv.z*w.z + yv.w*w.w;
      }
      out_s[((size_t)b * kT + t) * kS + tid] = acc;
      s_scr[(size_t)b * kS + tid] = acc;
    } else if (tid < kS + kR) {
      const int j = tid - kS;
      const float* wr = W_reward + (size_t)j * kF;
      float acc = b_reward[j];
      for (int k = 0; k < kF; k += 4) {
        float4 w  = *(const float4*)(wr + k);
        float4 yv = *(const float4*)(yrow + k);
        acc += yv.x*w.x + yv.y*w.y + yv.z*w.z + yv.w*w.w;
      }
      out_r[((size_t)b * kT + t) * kR + j] = tanhf(acc);
    }
  }
}

// ---------------- pres = LN(s@W_state^T+b)*g+b; x = gelu(pres + fa_t) ------
__device__ __forceinline__ void pres_gelu(
    const float* __restrict__ s_scr,
    const float* __restrict__ W_state, const float* __restrict__ b_state,
    const float* __restrict__ g_sn, const float* __restrict__ b_sn,
    const float* __restrict__ fa_t, float* __restrict__ xbuf, float* smem)
{
  if (blockIdx.x < kB) {
    const int b = blockIdx.x;
    const int tid = threadIdx.x;
    float* srow = smem;               // kS
    float* red1 = smem + kS;          // BT
    float* red2 = red1 + BT;          // BT
    for (int i = tid; i < kS; i += BT) srow[i] = s_scr[(size_t)b * kS + i];
    __syncthreads();
    constexpr int PER = kF / BT;      // 2
    float v[PER];
    float s1 = 0.f, s2 = 0.f;
    #pragma unroll
    for (int j = 0; j < PER; j++) {
      const int f = tid + j * BT;
      const float* wr = W_state + (size_t)f * kS;
      float acc = b_state[f];
      for (int k = 0; k < kS; k += 4) {
        float4 w  = *(const float4*)(wr + k);
        float4 sv = *(const float4*)(srow + k);
        acc += sv.x*w.x + sv.y*w.y + sv.z*w.z + sv.w*w.w;
      }
      v[j] = acc; s1 += acc; s2 += acc * acc;
    }
    red1[tid] = s1; red2[tid] = s2;
    __syncthreads();
    for (int off = BT / 2; off > 0; off >>= 1) {
      if (tid < off) { red1[tid] += red1[tid + off]; red2[tid] += red2[tid + off]; }
      __syncthreads();
    }
    const float mean = red1[0] * (1.0f / kF);
    const float var  = red2[0] * (1.0f / kF) - mean * mean;
    const float inv  = rsqrtf(var + kEPS);
    #pragma unroll
    for (int j = 0; j < PER; j++) {
      const int f = tid + j * BT;
      const float ln = (v[j] - mean) * inv * g_sn[f] + b_sn[f];
      xbuf[(size_t)b * kF + f] = gelu_f(ln + fa_t[(size_t)b * kF + f]);
    }
  }
}

// ---------------- persistent GRU + head kernel -----------------------------
__global__ __launch_bounds__(BT) void gru_persist(
    const float* __restrict__ gru_Wi, const float* __restrict__ gru_Wh,
    const float* __restrict__ gru_bi, const float* __restrict__ gru_bh,
    const float* __restrict__ W_state, const float* __restrict__ b_state,
    const float* __restrict__ g_sn, const float* __restrict__ b_sn,
    const float* __restrict__ W_reward, const float* __restrict__ b_reward,
    const float* __restrict__ W_sout, const float* __restrict__ b_sout,
    const float* __restrict__ seq0, const float* __restrict__ fa_ln,
    float* h0, float* h1, float* xbuf, float* s_scr,
    int* flags, int* go,
    float* __restrict__ out_r, float* __restrict__ out_s)
{
  __shared__ __align__(16) float smem[2048];
  const size_t BF = (size_t)kB * kF;
  const float* Wi0 = gru_Wi;
  const float* Wi1 = gru_Wi + (size_t)3 * kF * kF;
  const float* Wh0 = gru_Wh;
  const float* Wh1 = gru_Wh + (size_t)3 * kF * kF;
  const float* bi0 = gru_bi;
  const float* bi1 = gru_bi + 3 * kF;
  const float* bh0 = gru_bh;
  const float* bh1 = gru_bh + 3 * kF;
  int gen = 1;
  int p = 0;
  // ---- history + present: 49 steps, 2 layers each ----
  for (int t = 0; t < kSEQ; t++) {
    layer_step(seq0 + (size_t)t * BF, h0 + (size_t)p * BF, h0 + (size_t)(1 - p) * BF,
               Wi0, Wh0, bi0, bh0, smem);
    grid_barrier(flags, go, gen);
    layer_step(h0 + (size_t)(1 - p) * BF, h1 + (size_t)p * BF, h1 + (size_t)(1 - p) * BF,
               Wi1, Wh1, bi1, bh1, smem);
    grid_barrier(flags, go, gen);
    p ^= 1;
  }
  // ---- step 0 head ----
  head_rs(h1 + (size_t)p * BF, W_sout, b_sout, W_reward, b_reward,
          out_r, out_s, s_scr, 0, smem);
  grid_barrier(flags, go, gen);
  // ---- future steps 1..23 ----
  for (int t = 1; t < kT; t++) {
    pres_gelu(s_scr, W_state, b_state, g_sn, b_sn, fa_ln + (size_t)t * BF, xbuf, smem);
    grid_barrier(flags, go, gen);
    layer_step(xbuf, h0 + (size_t)p * BF, h0 + (size_t)(1 - p) * BF,
               Wi0, Wh0, bi0, bh0, smem);
    grid_barrier(flags, go, gen);
    layer_step(h0 + (size_t)(1 - p) * BF, h1 + (size_t)p * BF, h1 + (size_t)(1 - p) * BF,
               Wi1, Wh1, bi1, bh1, smem);
    grid_barrier(flags, go, gen);
    p ^= 1;
    head_rs(h1 + (size_t)p * BF, W_sout, b_sout, W_reward, b_reward,
            out_r, out_s, s_scr, t, smem);
    grid_barrier(flags, go, gen);
  }
}

// ---------------- encoder: fa_ln[t][b][f] = LN(future_a@Wa^T+ba)*g+b -------
__global__ __launch_bounds__(256) void encode_fa_kernel(
    const float* __restrict__ future_a,
    const float* __restrict__ W_action, const float* __restrict__ b_action,
    const float* __restrict__ g_an, const float* __restrict__ b_an,
    float* __restrict__ fa_ln)
{
  __shared__ __align__(16) float arow[kA];
  __shared__ float red1[256], red2[256];
  const int bid = blockIdx.x;
  const int b = bid & (kB - 1);
  const int t = bid >> 5;
  const int tid = threadIdx.x;
  if (tid < kA) arow[tid] = future_a[((size_t)b * kT + t) * kA + tid];
  __syncthreads();
  float v[4];
  float s1 = 0.f, s2 = 0.f;
  #pragma unroll
  for (int j = 0; j < 4; j++) {
    const int f = tid + j * 256;
    const float* wr = W_action + (size_t)f * kA;
    float acc = b_action[f];
    for (int k = 0; k < kA; k += 4) {
      float4 w  = *(const float4*)(wr + k);
      float4 xv = *(const float4*)(arow + k);
      acc += xv.x*w.x + xv.y*w.y + xv.z*w.z + xv.w*w.w;
    }
    v[j] = acc; s1 += acc; s2 += acc * acc;
  }
  red1[tid] = s1; red2[tid] = s2;
  __syncthreads();
  for (int off = 128; off > 0; off >>= 1) {
    if (tid < off) { red1[tid] += red1[tid + off]; red2[tid] += red2[tid + off]; }
    __syncthreads();
  }
  const float m = red1[0] * (1.0f / kF);
  const float va = red2[0] * (1.0f / kF) - m * m;
  const float inv = rsqrtf(va + kEPS);
  #pragma unroll
  for (int j = 0; j < 4; j++) {
    const int f = tid + j * 256;
    fa_ln[((size_t)t * kB + b) * kF + f] = (v[j] - m) * inv * g_an[f] + b_an[f];
  }
}

// ---------------- encoder: seq0 = gelu(LN_s(..) + LN_a(..)) ---------------
__global__ __launch_bounds__(256) void encode_seq0_kernel(
    const float* __restrict__ history_s, const float* __restrict__ history_a,
    const float* __restrict__ present_s,
    const float* __restrict__ W_state, const float* __restrict__ b_state,
    const float* __restrict__ g_sn, const float* __restrict__ b_sn,
    const float* __restrict__ W_action, const float* __restrict__ b_action,
    const float* __restrict__ g_an, const float* __restrict__ b_an,
    const float* __restrict__ fa_ln, float* __restrict__ seq0)
{
  __shared__ __align__(16) float srow[kS];
  __shared__ __align__(16) float arow[kA];
  __shared__ float red1[256], red2[256];
  const int bid = blockIdx.x;
  const int b = bid & (kB - 1);
  const int t = bid >> 5;                 // 0..48
  const int tid = threadIdx.x;
  const bool hist = (t < kH);
  const float* sp = hist ? (history_s + ((size_t)b * kH + t) * kS)
                         : (present_s + (size_t)b * kS);
  srow[tid] = sp[tid];
  if (hist && tid < kA) arow[tid] = history_a[((size_t)b * kH + t) * kA + tid];
  __syncthreads();

  float u[4];
  float s1 = 0.f, s2 = 0.f;
  #pragma unroll
  for (int j = 0; j < 4; j++) {
    const int f = tid + j * 256;
    const float* wr = W_state + (size_t)f * kS;
    float acc = b_state[f];
    for (int k = 0; k < kS; k += 4) {
      float4 w  = *(const float4*)(wr + k);
      float4 xv = *(const float4*)(srow + k);
      acc += xv.x*w.x + xv.y*w.y + xv.z*w.z + xv.w*w.w;
    }
    u[j] = acc; s1 += acc; s2 += acc * acc;
  }
  red1[tid] = s1; red2[tid] = s2;
  __syncthreads();
  for (int off = 128; off > 0; off >>= 1) {
    if (tid < off) { red1[tid] += red1[tid + off]; red2[tid] += red2[tid + off]; }
    __syncthreads();
  }
  const float mu = red1[0] * (1.0f / kF);
  const float vu = red2[0] * (1.0f / kF) - mu * mu;
  const float iu = rsqrtf(vu + kEPS);
  __syncthreads();

  if (hist) {
    float v[4];
    s1 = 0.f; s2 = 0.f;
    #pragma unroll
    for (int j = 0; j < 4; j++) {
      const int f = tid + j * 256;
      const float* wr = W_action + (size_t)f * kA;
      float acc = b_action[f];
      for (int k = 0; k < kA; k += 4) {
        float4 w  = *(const float4*)(wr + k);
        float4 xv = *(const float4*)(arow + k);
        acc += xv.x*w.x + xv.y*w.y + xv.z*w.z + xv.w*w.w;
      }
      v[j] = acc; s1 += acc; s2 += acc * acc;
    }
    red1[tid] = s1; red2[tid] = s2;
    __syncthreads();
    for (int off = 128; off > 0; off >>= 1) {
      if (tid < off) { red1[tid] += red1[tid + off]; red2[tid] += red2[tid + off]; }
      __syncthreads();
    }
    const float mv = red1[0] * (1.0f / kF);
    const float vv = red2[0] * (1.0f / kF) - mv * mv;
    const float iv = rsqrtf(vv + kEPS);
    #pragma unroll
    for (int j = 0; j < 4; j++) {
      const int f = tid + j * 256;
      const float un = (u[j] - mu) * iu * g_sn[f] + b_sn[f];
      const float vn = (v[j] - mv) * iv * g_an[f] + b_an[f];
      seq0[((size_t)t * kB + b) * kF + f] = gelu_f(un + vn);
    }
  } else {
    #pragma unroll
    for (int j = 0; j < 4; j++) {
      const int f = tid + j * 256;
      const float un = (u[j] - mu) * iu * g_sn[f] + b_sn[f];
      seq0[((size_t)t * kB + b) * kF + f] = gelu_f(un + fa_ln[(size_t)b * kF + f]);
    }
  }
}

// ---------------- host launcher -------------------------------------------
extern "C" void kernel_launch(void* const* d_in, const int* in_sizes, int n_in,
                              void* d_out, int out_size, void* d_ws, size_t ws_size,
                              hipStream_t stream) {
  (void)in_sizes; (void)n_in; (void)out_size;
  const float* history_s = (const float*)d_in[0];
  const float* history_a = (const float*)d_in[1];
  const float* present_s = (const float*)d_in[2];
  /* d_in[3] future_s: unused by the reference forward */
  const float* future_a  = (const float*)d_in[4];
  const float* W_state   = (const float*)d_in[5];
  const float* b_state   = (const float*)d_in[6];
  const float* g_sn      = (const float*)d_in[7];
  const float* b_sn      = (const float*)d_in[8];
  const float* W_action  = (const float*)d_in[9];
  const float* b_action  = (const float*)d_in[10];
  const float* g_an      = (const float*)d_in[11];
  const float* b_an      = (const float*)d_in[12];
  const float* gru_Wi    = (const float*)d_in[13];
  const float* gru_Wh    = (const float*)d_in[14];
  const float* gru_bi    = (const float*)d_in[15];
  const float* gru_bh    = (const float*)d_in[16];
  const float* W_reward  = (const float*)d_in[17];
  const float* b_reward  = (const float*)d_in[18];
  const float* W_sout    = (const float*)d_in[19];
  const float* b_sout    = (const float*)d_in[20];

  float* ws    = (float*)d_ws;
  float* seq0  = ws;                                    // [49][B][F]
  float* fa_ln = seq0 + (size_t)kSEQ * kB * kF;         // [24][B][F]
  float* h0    = fa_ln + (size_t)kT * kB * kF;          // [2][B][F] double-buffered
  float* h1    = h0 + 2 * (size_t)kB * kF;              // [2][B][F]
  float* xbuf  = h1 + 2 * (size_t)kB * kF;              // [B][F]
  float* s_scr = xbuf + (size_t)kB * kF;                // [B][S]
  int*   flags = (int*)(s_scr + (size_t)kB * kS);       // [G]
  int*   go    = flags + G;                             // [1]
  const size_t need = (size_t)((char*)(go + 1) - (char*)d_ws);
  if (ws_size < need) return;  // workspace too small; cannot proceed

  // Zero only what must start at 0: h0/h1 (parity-0 hidden state) .. flags/go.
  // seq0/fa_ln are fully overwritten by the encoder kernels.
  hipMemsetAsync((void*)h0, 0, (size_t)((char*)(go + 1) - (char*)h0), stream);

  float* out_r = (float*)d_out;                         // [B][T][R]
  float* out_s = out_r + (size_t)kB * kT * kR;          // [B][T][S]

  hipLaunchKernelGGL(encode_fa_kernel, dim3(kT * kB), dim3(256), 0, stream,
                     future_a, W_action, b_action, g_an, b_an, fa_ln);
  hipLaunchKernelGGL(encode_seq0_kernel, dim3(kSEQ * kB), dim3(256), 0, stream,
                     history_s, history_a, present_s,
                     W_state, b_state, g_sn, b_sn,
                     W_action, b_action, g_an, b_an, fa_ln, seq0);
  hipLaunchKernelGGL(gru_persist, dim3(G), dim3(BT), 0, stream,
                     gru_Wi, gru_Wh, gru_bi, gru_bh,
                     W_state, b_state, g_sn, b_sn,
                     W_reward, b_reward, W_sout, b_sout,
                     seq0, fa_ln, h0, h1, xbuf, s_scr, flags, go,
                     out_r, out_s);
}

// Round 2
// 6327.719 us; speedup vs baseline: 3.9901x; 3.9901x over previous
//
#include <hip/hip_runtime.h>
#include <cmath>

// Problem dims (fixed by the reference)
constexpr int kB = 32, kH = 48, kT = 24, kS = 256, kA = 64, kR = 8, kF = 1024;
constexpr int kSEQ = kH + 1;           // 49 = history + present step
constexpr float kEPS = 1e-5f;

// Persistent-kernel config: 512 blocks x 256 thr = 2 blocks/CU (co-resident).
constexpr int G  = 512;
constexpr int BT = 256;
constexpr int FT = 2;                  // f-columns owned per block per layer

__device__ __forceinline__ float gelu_f(float x) {
  return 0.5f * x * (1.0f + erff(x * 0.7071067811865476f));
}
__device__ __forceinline__ float sigmoid_f(float x) {
  return 1.0f / (1.0f + expf(-x));
}
// bf16 helpers: weights live in LDS as packed pairs (2 x bf16 per uint)
__device__ __forceinline__ float bf_lo(unsigned u) { return __uint_as_float(u << 16); }
__device__ __forceinline__ float bf_hi(unsigned u) { return __uint_as_float(u & 0xffff0000u); }
__device__ __forceinline__ unsigned bfbits(float x) {  // RNE f32->bf16
  unsigned u = __float_as_uint(x);
  return (u + 0x7fffu + ((u >> 16) & 1u)) >> 16;
}

// ---------------- grid-wide barrier --------------------------------------
// Relaxed polls (no per-iteration cache invalidation); single acquire fence
// on exit. Release store publishes this block's stage output.
__device__ __forceinline__ void grid_barrier(int* flags, int* go, int& gen) {
  __syncthreads();
  if (threadIdx.x == 0) {
    __hip_atomic_store(&flags[blockIdx.x], gen, __ATOMIC_RELEASE, __HIP_MEMORY_SCOPE_AGENT);
  }
  if (blockIdx.x == 0) {
    for (int i = threadIdx.x; i < G; i += BT) {
      while (__hip_atomic_load(&flags[i], __ATOMIC_RELAXED, __HIP_MEMORY_SCOPE_AGENT) < gen) {
        __builtin_amdgcn_s_sleep(1);
      }
    }
    __syncthreads();
    if (threadIdx.x == 0) {
      __hip_atomic_store(go, gen, __ATOMIC_RELEASE, __HIP_MEMORY_SCOPE_AGENT);
    }
  }
  if (threadIdx.x == 0) {
    while (__hip_atomic_load(go, __ATOMIC_RELAXED, __HIP_MEMORY_SCOPE_AGENT) < gen) {
      __builtin_amdgcn_s_sleep(1);
    }
    __builtin_amdgcn_fence(__ATOMIC_ACQUIRE, "agent");
  }
  __syncthreads();
  gen++;
}

// ---------------- one GRU layer step --------------------------------------
// Block owns FT=2 f-columns; weights for 3 gates x {Wi,Wh} in LDS (bf16).
// thread = (kh, half, o): kh k-half, half = Wi*x vs Wh*h, o = b*2+fi.
#define PARTI(kh, half, gate) ((((kh)*2 + (half))*3 + (gate)) * 64)

__device__ __forceinline__ void layer_step(
    const float* __restrict__ x, const float* __restrict__ hcur, float* __restrict__ hnxt,
    const unsigned* __restrict__ wl,   // LDS weights for this layer (6144 uints)
    const float* __restrict__ bi, const float* __restrict__ bh,
    float* smem)
{
  const int tid  = threadIdx.x;
  const int o    = tid & 63;
  const int half = (tid >> 6) & 1;
  const int kh   = tid >> 7;
  const int b    = o >> 1;
  const int fi   = o & 1;

  const float* src = (half ? hcur : x) + (size_t)b * kF + kh * 512;
  const unsigned* w0 = wl + ((half*3 + 0)*2 + fi)*512 + kh*256;
  const unsigned* w1 = wl + ((half*3 + 1)*2 + fi)*512 + kh*256;
  const unsigned* w2 = wl + ((half*3 + 2)*2 + fi)*512 + kh*256;

  float ar = 0.f, az = 0.f, an = 0.f;
  #pragma unroll 8
  for (int k = 0; k < 512; k += 4) {
    float4 xv = *(const float4*)(src + k);
    uint2 a0 = *(const uint2*)(w0 + (k >> 1));
    uint2 a1 = *(const uint2*)(w1 + (k >> 1));
    uint2 a2 = *(const uint2*)(w2 + (k >> 1));
    ar += xv.x*bf_lo(a0.x) + xv.y*bf_hi(a0.x) + xv.z*bf_lo(a0.y) + xv.w*bf_hi(a0.y);
    az += xv.x*bf_lo(a1.x) + xv.y*bf_hi(a1.x) + xv.z*bf_lo(a1.y) + xv.w*bf_hi(a1.y);
    an += xv.x*bf_lo(a2.x) + xv.y*bf_hi(a2.x) + xv.z*bf_lo(a2.y) + xv.w*bf_hi(a2.y);
  }
  smem[PARTI(kh, half, 0) + o] = ar;
  smem[PARTI(kh, half, 1) + o] = az;
  smem[PARTI(kh, half, 2) + o] = an;
  __syncthreads();
  if (tid < 64) {
    const int bb = tid >> 1, ff = blockIdx.x * FT + (tid & 1);
    float gir = smem[PARTI(0,0,0)+tid] + smem[PARTI(1,0,0)+tid] + bi[ff];
    float giz = smem[PARTI(0,0,1)+tid] + smem[PARTI(1,0,1)+tid] + bi[kF + ff];
    float gin = smem[PARTI(0,0,2)+tid] + smem[PARTI(1,0,2)+tid] + bi[2*kF + ff];
    float ghr = smem[PARTI(0,1,0)+tid] + smem[PARTI(1,1,0)+tid] + bh[ff];
    float ghz = smem[PARTI(0,1,1)+tid] + smem[PARTI(1,1,1)+tid] + bh[kF + ff];
    float ghn = smem[PARTI(0,1,2)+tid] + smem[PARTI(1,1,2)+tid] + bh[2*kF + ff];
    float r = sigmoid_f(gir + ghr);
    float z = sigmoid_f(giz + ghz);
    float n = tanhf(gin + r * ghn);
    float hold = hcur[(size_t)bb * kF + ff];
    hnxt[(size_t)bb * kF + ff] = (1.f - z) * n + z * hold;
  }
  __syncthreads();   // protect smem reuse by next stage
}

// ---------------- head spread over all 512 blocks --------------------------
// blk = b*16 + cg ; cg owns 16 s-columns; cg==0 also does the 8 rewards.
__device__ __forceinline__ void head_spread(
    const float* __restrict__ y,
    const float* __restrict__ W_sout, const float* __restrict__ b_sout,
    const float* __restrict__ W_reward, const float* __restrict__ b_reward,
    float* __restrict__ out_r, float* __restrict__ out_s, float* __restrict__ s_scr,
    int t, float* smem)
{
  const int b  = blockIdx.x >> 4;
  const int cg = blockIdx.x & 15;
  const int tid = threadIdx.x;
  float* yrow = smem;            // 1024
  float* part = smem + 1024;     // 256
  float* part2 = smem + 1280;    // 256
  *(float4*)(yrow + tid*4) = *(const float4*)(y + (size_t)b * kF + tid*4);
  __syncthreads();
  {
    const int col = tid & 15, ks = tid >> 4;      // 16 cols x 16 k-slices of 64
    const int c = cg*16 + col;
    const float* wr = W_sout + (size_t)c * kF + ks*64;
    const float* yr = yrow + ks*64;
    float acc = 0.f;
    #pragma unroll
    for (int k = 0; k < 64; k += 4) {
      float4 w = *(const float4*)(wr + k);
      float4 yv = *(const float4*)(yr + k);
      acc += yv.x*w.x + yv.y*w.y + yv.z*w.z + yv.w*w.w;
    }
    part[tid] = acc;
  }
  if (cg == 0) {
    const int r = tid & 7, ks = tid >> 3;         // 8 rows x 32 k-slices of 32
    const float* wr = W_reward + (size_t)r * kF + ks*32;
    const float* yr = yrow + ks*32;
    float acc = 0.f;
    #pragma unroll
    for (int k = 0; k < 32; k += 4) {
      float4 w = *(const float4*)(wr + k);
      float4 yv = *(const float4*)(yr + k);
      acc += yv.x*w.x + yv.y*w.y + yv.z*w.z + yv.w*w.w;
    }
    part2[tid] = acc;
  }
  __syncthreads();
  if (tid < 16) {
    const int c = cg*16 + tid;
    float a = b_sout[c];
    #pragma unroll
    for (int j = 0; j < 16; j++) a += part[j*16 + tid];
    out_s[((size_t)b * kT + t) * kS + c] = a;
    s_scr[(size_t)b * kS + c] = a;
  }
  if (cg == 0 && tid < 8) {
    float a = b_reward[tid];
    #pragma unroll
    for (int j = 0; j < 32; j++) a += part2[j*8 + tid];
    out_r[((size_t)b * kT + t) * kR + tid] = tanhf(a);
  }
  __syncthreads();
}

// ---------------- pres = LN(s@W_state^T+b)*g+b; x = gelu(pres + fa_t) ------
__device__ __forceinline__ void pres_gelu(
    const float* __restrict__ s_scr,
    const float* __restrict__ W_state, const float* __restrict__ b_state,
    const float* __restrict__ g_sn, const float* __restrict__ b_sn,
    const float* __restrict__ fa_t, float* __restrict__ xbuf, float* smem)
{
  if (blockIdx.x < kB) {
    const int b = blockIdx.x;
    const int tid = threadIdx.x;
    float* srow = smem;               // 256
    float* red1 = smem + 256;         // 256
    float* red2 = smem + 512;         // 256
    srow[tid] = s_scr[(size_t)b * kS + tid];
    __syncthreads();
    constexpr int PER = kF / BT;      // 4
    float v[PER];
    float s1 = 0.f, s2 = 0.f;
    #pragma unroll
    for (int j = 0; j < PER; j++) {
      const int f = tid + j * BT;
      const float* wr = W_state + (size_t)f * kS;
      float acc = b_state[f];
      for (int k = 0; k < kS; k += 4) {
        float4 w  = *(const float4*)(wr + k);
        float4 sv = *(const float4*)(srow + k);
        acc += sv.x*w.x + sv.y*w.y + sv.z*w.z + sv.w*w.w;
      }
      v[j] = acc; s1 += acc; s2 += acc * acc;
    }
    red1[tid] = s1; red2[tid] = s2;
    __syncthreads();
    for (int off = BT / 2; off > 0; off >>= 1) {
      if (tid < off) { red1[tid] += red1[tid + off]; red2[tid] += red2[tid + off]; }
      __syncthreads();
    }
    const float mean = red1[0] * (1.0f / kF);
    const float var  = red2[0] * (1.0f / kF) - mean * mean;
    const float inv  = rsqrtf(var + kEPS);
    #pragma unroll
    for (int j = 0; j < PER; j++) {
      const int f = tid + j * BT;
      const float ln = (v[j] - mean) * inv * g_sn[f] + b_sn[f];
      xbuf[(size_t)b * kF + f] = gelu_f(ln + fa_t[(size_t)b * kF + f]);
    }
    __syncthreads();
  }
}

// ---------------- persistent GRU + head kernel -----------------------------
__global__ __launch_bounds__(BT, 2) void gru_persist(
    const float* __restrict__ gru_Wi, const float* __restrict__ gru_Wh,
    const float* __restrict__ gru_bi, const float* __restrict__ gru_bh,
    const float* __restrict__ W_state, const float* __restrict__ b_state,
    const float* __restrict__ g_sn, const float* __restrict__ b_sn,
    const float* __restrict__ W_reward, const float* __restrict__ b_reward,
    const float* __restrict__ W_sout, const float* __restrict__ b_sout,
    const float* __restrict__ seq0, const float* __restrict__ fa_ln,
    float* h0, float* h1, float* xbuf, float* s_scr,
    int* flags, int* go,
    float* __restrict__ out_r, float* __restrict__ out_s)
{
  // LDS: bf16 weights for both layers (packed pairs) + scratch
  __shared__ unsigned wlds[2 * 6144];     // 48 KB: [l][m][g][fi][512 uints]
  __shared__ __align__(16) float smem[1536];  // 6 KB
  const int tid = threadIdx.x;

  // ---- preamble: stage this block's 24 weight rows into LDS as bf16 ----
  #pragma unroll 1
  for (int r = 0; r < 24; r++) {
    const int l = r / 12, m = (r / 6) % 2, g = (r / 2) % 3, fi = r % 2;
    const int f = blockIdx.x * FT + fi;
    const float* grow = (m ? gru_Wh : gru_Wi) + (size_t)l * 3 * kF * kF
                        + ((size_t)g * kF + f) * kF;
    float4 w = *(const float4*)(grow + tid * 4);
    const int base = l * 6144 + ((m*3 + g)*2 + fi) * 512;
    wlds[base + tid*2]     = bfbits(w.x) | (bfbits(w.y) << 16);
    wlds[base + tid*2 + 1] = bfbits(w.z) | (bfbits(w.w) << 16);
  }
  __syncthreads();

  const size_t BF = (size_t)kB * kF;
  const unsigned* wl0 = wlds;
  const unsigned* wl1 = wlds + 6144;
  const float* bi0 = gru_bi;
  const float* bi1 = gru_bi + 3 * kF;
  const float* bh0 = gru_bh;
  const float* bh1 = gru_bh + 3 * kF;
  int gen = 1;
  int p = 0;
  // ---- history + present: 49 steps, 2 layers each ----
  for (int t = 0; t < kSEQ; t++) {
    layer_step(seq0 + (size_t)t * BF, h0 + (size_t)p * BF, h0 + (size_t)(1 - p) * BF,
               wl0, bi0, bh0, smem);
    grid_barrier(flags, go, gen);
    layer_step(h0 + (size_t)(1 - p) * BF, h1 + (size_t)p * BF, h1 + (size_t)(1 - p) * BF,
               wl1, bi1, bh1, smem);
    grid_barrier(flags, go, gen);
    p ^= 1;
  }
  // ---- step 0 head ----
  head_spread(h1 + (size_t)p * BF, W_sout, b_sout, W_reward, b_reward,
              out_r, out_s, s_scr, 0, smem);
  grid_barrier(flags, go, gen);
  // ---- future steps 1..23 ----
  for (int t = 1; t < kT; t++) {
    pres_gelu(s_scr, W_state, b_state, g_sn, b_sn, fa_ln + (size_t)t * BF, xbuf, smem);
    grid_barrier(flags, go, gen);
    layer_step(xbuf, h0 + (size_t)p * BF, h0 + (size_t)(1 - p) * BF,
               wl0, bi0, bh0, smem);
    grid_barrier(flags, go, gen);
    layer_step(h0 + (size_t)(1 - p) * BF, h1 + (size_t)p * BF, h1 + (size_t)(1 - p) * BF,
               wl1, bi1, bh1, smem);
    grid_barrier(flags, go, gen);
    p ^= 1;
    head_spread(h1 + (size_t)p * BF, W_sout, b_sout, W_reward, b_reward,
                out_r, out_s, s_scr, t, smem);
    grid_barrier(flags, go, gen);
  }
}

// ---------------- encoder: fa_ln[t][b][f] = LN(future_a@Wa^T+ba)*g+b -------
__global__ __launch_bounds__(256) void encode_fa_kernel(
    const float* __restrict__ future_a,
    const float* __restrict__ W_action, const float* __restrict__ b_action,
    const float* __restrict__ g_an, const float* __restrict__ b_an,
    float* __restrict__ fa_ln)
{
  __shared__ __align__(16) float arow[kA];
  __shared__ float red1[256], red2[256];
  const int bid = blockIdx.x;
  const int b = bid & (kB - 1);
  const int t = bid >> 5;
  const int tid = threadIdx.x;
  if (tid < kA) arow[tid] = future_a[((size_t)b * kT + t) * kA + tid];
  __syncthreads();
  float v[4];
  float s1 = 0.f, s2 = 0.f;
  #pragma unroll
  for (int j = 0; j < 4; j++) {
    const int f = tid + j * 256;
    const float* wr = W_action + (size_t)f * kA;
    float acc = b_action[f];
    for (int k = 0; k < kA; k += 4) {
      float4 w  = *(const float4*)(wr + k);
      float4 xv = *(const float4*)(arow + k);
      acc += xv.x*w.x + xv.y*w.y + xv.z*w.z + xv.w*w.w;
    }
    v[j] = acc; s1 += acc; s2 += acc * acc;
  }
  red1[tid] = s1; red2[tid] = s2;
  __syncthreads();
  for (int off = 128; off > 0; off >>= 1) {
    if (tid < off) { red1[tid] += red1[tid + off]; red2[tid] += red2[tid + off]; }
    __syncthreads();
  }
  const float m = red1[0] * (1.0f / kF);
  const float va = red2[0] * (1.0f / kF) - m * m;
  const float inv = rsqrtf(va + kEPS);
  #pragma unroll
  for (int j = 0; j < 4; j++) {
    const int f = tid + j * 256;
    fa_ln[((size_t)t * kB + b) * kF + f] = (v[j] - m) * inv * g_an[f] + b_an[f];
  }
}

// ---------------- encoder: seq0 = gelu(LN_s(..) + LN_a(..)) ---------------
__global__ __launch_bounds__(256) void encode_seq0_kernel(
    const float* __restrict__ history_s, const float* __restrict__ history_a,
    const float* __restrict__ present_s,
    const float* __restrict__ W_state, const float* __restrict__ b_state,
    const float* __restrict__ g_sn, const float* __restrict__ b_sn,
    const float* __restrict__ W_action, const float* __restrict__ b_action,
    const float* __restrict__ g_an, const float* __restrict__ b_an,
    const float* __restrict__ fa_ln, float* __restrict__ seq0)
{
  __shared__ __align__(16) float srow[kS];
  __shared__ __align__(16) float arow[kA];
  __shared__ float red1[256], red2[256];
  const int bid = blockIdx.x;
  const int b = bid & (kB - 1);
  const int t = bid >> 5;                 // 0..48
  const int tid = threadIdx.x;
  const bool hist = (t < kH);
  const float* sp = hist ? (history_s + ((size_t)b * kH + t) * kS)
                         : (present_s + (size_t)b * kS);
  srow[tid] = sp[tid];
  if (hist && tid < kA) arow[tid] = history_a[((size_t)b * kH + t) * kA + tid];
  __syncthreads();

  float u[4];
  float s1 = 0.f, s2 = 0.f;
  #pragma unroll
  for (int j = 0; j < 4; j++) {
    const int f = tid + j * 256;
    const float* wr = W_state + (size_t)f * kS;
    float acc = b_state[f];
    for (int k = 0; k < kS; k += 4) {
      float4 w  = *(const float4*)(wr + k);
      float4 xv = *(const float4*)(srow + k);
      acc += xv.x*w.x + xv.y*w.y + xv.z*w.z + xv.w*w.w;
    }
    u[j] = acc; s1 += acc; s2 += acc * acc;
  }
  red1[tid] = s1; red2[tid] = s2;
  __syncthreads();
  for (int off = 128; off > 0; off >>= 1) {
    if (tid < off) { red1[tid] += red1[tid + off]; red2[tid] += red2[tid + off]; }
    __syncthreads();
  }
  const float mu = red1[0] * (1.0f / kF);
  const float vu = red2[0] * (1.0f / kF) - mu * mu;
  const float iu = rsqrtf(vu + kEPS);
  __syncthreads();

  if (hist) {
    float v[4];
    s1 = 0.f; s2 = 0.f;
    #pragma unroll
    for (int j = 0; j < 4; j++) {
      const int f = tid + j * 256;
      const float* wr = W_action + (size_t)f * kA;
      float acc = b_action[f];
      for (int k = 0; k < kA; k += 4) {
        float4 w  = *(const float4*)(wr + k);
        float4 xv = *(const float4*)(arow + k);
        acc += xv.x*w.x + xv.y*w.y + xv.z*w.z + xv.w*w.w;
      }
      v[j] = acc; s1 += acc; s2 += acc * acc;
    }
    red1[tid] = s1; red2[tid] = s2;
    __syncthreads();
    for (int off = 128; off > 0; off >>= 1) {
      if (tid < off) { red1[tid] += red1[tid + off]; red2[tid] += red2[tid + off]; }
      __syncthreads();
    }
    const float mv = red1[0] * (1.0f / kF);
    const float vv = red2[0] * (1.0f / kF) - mv * mv;
    const float iv = rsqrtf(vv + kEPS);
    #pragma unroll
    for (int j = 0; j < 4; j++) {
      const int f = tid + j * 256;
      const float un = (u[j] - mu) * iu * g_sn[f] + b_sn[f];
      const float vn = (v[j] - mv) * iv * g_an[f] + b_an[f];
      seq0[((size_t)t * kB + b) * kF + f] = gelu_f(un + vn);
    }
  } else {
    #pragma unroll
    for (int j = 0; j < 4; j++) {
      const int f = tid + j * 256;
      const float un = (u[j] - mu) * iu * g_sn[f] + b_sn[f];
      seq0[((size_t)t * kB + b) * kF + f] = gelu_f(un + fa_ln[(size_t)b * kF + f]);
    }
  }
}

// ---------------- host launcher -------------------------------------------
extern "C" void kernel_launch(void* const* d_in, const int* in_sizes, int n_in,
                              void* d_out, int out_size, void* d_ws, size_t ws_size,
                              hipStream_t stream) {
  (void)in_sizes; (void)n_in; (void)out_size;
  const float* history_s = (const float*)d_in[0];
  const float* history_a = (const float*)d_in[1];
  const float* present_s = (const float*)d_in[2];
  /* d_in[3] future_s: unused by the reference forward */
  const float* future_a  = (const float*)d_in[4];
  const float* W_state   = (const float*)d_in[5];
  const float* b_state   = (const float*)d_in[6];
  const float* g_sn      = (const float*)d_in[7];
  const float* b_sn      = (const float*)d_in[8];
  const float* W_action  = (const float*)d_in[9];
  const float* b_action  = (const float*)d_in[10];
  const float* g_an      = (const float*)d_in[11];
  const float* b_an      = (const float*)d_in[12];
  const float* gru_Wi    = (const float*)d_in[13];
  const float* gru_Wh    = (const float*)d_in[14];
  const float* gru_bi    = (const float*)d_in[15];
  const float* gru_bh    = (const float*)d_in[16];
  const float* W_reward  = (const float*)d_in[17];
  const float* b_reward  = (const float*)d_in[18];
  const float* W_sout    = (const float*)d_in[19];
  const float* b_sout    = (const float*)d_in[20];

  float* ws    = (float*)d_ws;
  float* seq0  = ws;                                    // [49][B][F]
  float* fa_ln = seq0 + (size_t)kSEQ * kB * kF;         // [24][B][F]
  float* h0    = fa_ln + (size_t)kT * kB * kF;          // [2][B][F]
  float* h1    = h0 + 2 * (size_t)kB * kF;              // [2][B][F]
  float* xbuf  = h1 + 2 * (size_t)kB * kF;              // [B][F]
  float* s_scr = xbuf + (size_t)kB * kF;                // [B][S]
  int*   flags = (int*)(s_scr + (size_t)kB * kS);       // [G]
  int*   go    = flags + G;                             // [1]
  const size_t need = (size_t)((char*)(go + 1) - (char*)d_ws);
  if (ws_size < need) return;

  // Zero hidden states + barrier state (gen counts up from 1 each launch).
  hipMemsetAsync((void*)h0, 0, (size_t)((char*)(go + 1) - (char*)h0), stream);

  float* out_r = (float*)d_out;                         // [B][T][R]
  float* out_s = out_r + (size_t)kB * kT * kR;          // [B][T][S]

  hipLaunchKernelGGL(encode_fa_kernel, dim3(kT * kB), dim3(256), 0, stream,
                     future_a, W_action, b_action, g_an, b_an, fa_ln);
  hipLaunchKernelGGL(encode_seq0_kernel, dim3(kSEQ * kB), dim3(256), 0, stream,
                     history_s, history_a, present_s,
                     W_state, b_state, g_sn, b_sn,
                     W_action, b_action, g_an, b_an, fa_ln, seq0);
  hipLaunchKernelGGL(gru_persist, dim3(G), dim3(BT), 0, stream,
                     gru_Wi, gru_Wh, gru_bi, gru_bh,
                     W_state, b_state, g_sn, b_sn,
                     W_reward, b_reward, W_sout, b_sout,
                     seq0, fa_ln, h0, h1, xbuf, s_scr, flags, go,
                     out_r, out_s);
}

// Round 3
// 2144.357 us; speedup vs baseline: 11.7743x; 2.9509x over previous
//
#include <hip/hip_runtime.h>
#include <cmath>

// Problem dims (fixed by the reference)
constexpr int kB = 32, kH = 48, kT = 24, kS = 256, kA = 64, kR = 8, kF = 1024;
constexpr int kSEQ = kH + 1;           // 49 = history + present step
constexpr float kEPS = 1e-5f;

// Persistent-kernel config: 128 blocks x 512 thr (8 waves).
// Blocks 0..63: layer-0 f-tiles (16 cols each). Blocks 64..127: layer-1.
// Wave w = k-slice of 128 (K=1024 over 8 waves). Blocks 0..31 also run the
// fused head stage (one batch each).
constexpr int G  = 128;
constexpr int BT = 512;

typedef __attribute__((ext_vector_type(8))) short short8;   // 8 x bf16
typedef __attribute__((ext_vector_type(4))) float f32x4;

union U4S8 { uint4 u; short8 s; };

__device__ __forceinline__ unsigned bfbits(float x) {  // RNE f32->bf16
  unsigned u = __float_as_uint(x);
  return (u + 0x7fffu + ((u >> 16) & 1u)) >> 16;
}
__device__ __forceinline__ float bf2f(unsigned short h) {
  return __uint_as_float(((unsigned)h) << 16);
}
__device__ __forceinline__ float gelu_f(float x) {
  return 0.5f * x * (1.0f + erff(x * 0.7071067811865476f));
}
__device__ __forceinline__ float sigmoid_f(float x) {
  return 1.0f / (1.0f + expf(-x));
}
// dot of 8 bf16 weights (packed) with 8 f32 activations
__device__ __forceinline__ float dot8(const unsigned short* w, const float* y) {
  uint4 u = *(const uint4*)w;
  float r = 0.f;
  r += y[0] * __uint_as_float(u.x << 16);
  r += y[1] * __uint_as_float(u.x & 0xffff0000u);
  r += y[2] * __uint_as_float(u.y << 16);
  r += y[3] * __uint_as_float(u.y & 0xffff0000u);
  r += y[4] * __uint_as_float(u.z << 16);
  r += y[5] * __uint_as_float(u.z & 0xffff0000u);
  r += y[6] * __uint_as_float(u.w << 16);
  r += y[7] * __uint_as_float(u.w & 0xffff0000u);
  return r;
}

// ---------------- grid-wide barrier (R2-proven structure) ------------------
__device__ __forceinline__ void grid_barrier(int* flags, int* go, int& gen) {
  __syncthreads();
  if (threadIdx.x == 0) {
    __hip_atomic_store(&flags[blockIdx.x], gen, __ATOMIC_RELEASE, __HIP_MEMORY_SCOPE_AGENT);
  }
  if (blockIdx.x == 0) {
    for (int i = threadIdx.x; i < G; i += BT) {
      while (__hip_atomic_load(&flags[i], __ATOMIC_RELAXED, __HIP_MEMORY_SCOPE_AGENT) < gen) {
        __builtin_amdgcn_s_sleep(1);
      }
    }
    __syncthreads();
    if (threadIdx.x == 0) {
      __hip_atomic_store(go, gen, __ATOMIC_RELEASE, __HIP_MEMORY_SCOPE_AGENT);
    }
  }
  if (threadIdx.x == 0) {
    while (__hip_atomic_load(go, __ATOMIC_RELAXED, __HIP_MEMORY_SCOPE_AGENT) < gen) {
      __builtin_amdgcn_s_sleep(1);
    }
    __builtin_amdgcn_fence(__ATOMIC_ACQUIRE, "agent");
  }
  __syncthreads();
  gen++;
}

// ---------------- one GRU layer step via MFMA ------------------------------
// Block owns 16 f-cols of one layer. Wave wv = k-slice [wv*128, wv*128+128).
// B-frags (weights) resident in VGPRs. Sets: 0=r(i+h), 1=z(i+h), 2=n_i, 3=n_h.
// C/D layout (m89): D[m = (lane>>4)*4+reg][n = lane&15]; A: m=lane&15,
// k=(lane>>4)*8+j; B (from row-major W[n][k]): n=lane&15, k=(lane>>4)*8+j.
__device__ __forceinline__ void layer_stage(
    const unsigned short* __restrict__ xsrc,   // [32][1024] bf16 (A for Wi)
    const unsigned short* __restrict__ hsrc,   // [32][1024] bf16 (A for Wh)
    unsigned short* __restrict__ hdst,         // [32][1024] bf16
    const short8 (&Bf)[2][3][4],
    float bR, float bZ, float bIN, float bHN,
    float& h_old, float* part, int fb)
{
  const int tid = threadIdx.x;
  const int wv = tid >> 6, l = tid & 63, q = l >> 4, c = l & 15;

  // A fragments: [mat][mtile][kstep]
  short8 Afr[2][2][4];
  const unsigned short* srcs[2] = {xsrc, hsrc};
  #pragma unroll
  for (int m = 0; m < 2; m++)
    #pragma unroll
    for (int mt = 0; mt < 2; mt++)
      #pragma unroll
      for (int j = 0; j < 4; j++)
        Afr[m][mt][j] = *(const short8*)(srcs[m] + (mt*16 + c)*1024 + wv*128 + j*32 + q*8);

  f32x4 C[4][2];
  #pragma unroll
  for (int s = 0; s < 4; s++)
    #pragma unroll
    for (int mt = 0; mt < 2; mt++)
      C[s][mt] = (f32x4){0.f, 0.f, 0.f, 0.f};

  #pragma unroll
  for (int mt = 0; mt < 2; mt++)
    #pragma unroll
    for (int j = 0; j < 4; j++) {
      C[0][mt] = __builtin_amdgcn_mfma_f32_16x16x32_bf16(Afr[0][mt][j], Bf[0][0][j], C[0][mt], 0, 0, 0);
      C[0][mt] = __builtin_amdgcn_mfma_f32_16x16x32_bf16(Afr[1][mt][j], Bf[1][0][j], C[0][mt], 0, 0, 0);
      C[1][mt] = __builtin_amdgcn_mfma_f32_16x16x32_bf16(Afr[0][mt][j], Bf[0][1][j], C[1][mt], 0, 0, 0);
      C[1][mt] = __builtin_amdgcn_mfma_f32_16x16x32_bf16(Afr[1][mt][j], Bf[1][1][j], C[1][mt], 0, 0, 0);
      C[2][mt] = __builtin_amdgcn_mfma_f32_16x16x32_bf16(Afr[0][mt][j], Bf[0][2][j], C[2][mt], 0, 0, 0);
      C[3][mt] = __builtin_amdgcn_mfma_f32_16x16x32_bf16(Afr[1][mt][j], Bf[1][2][j], C[3][mt], 0, 0, 0);
    }

  // k-slice partials -> LDS. Swizzle ks' = (wv + l + (l>>3)) & 7 makes each
  // write instr hit 32 distinct banks (2-way over 64 lanes = free).
  const int perm = (wv + l + (l >> 3)) & 7;
  #pragma unroll
  for (int s = 0; s < 4; s++)
    #pragma unroll
    for (int mt = 0; mt < 2; mt++)
      #pragma unroll
      for (int r = 0; r < 4; r++)
        part[((s*2 + mt)*4 + r)*512 + l*8 + perm] = C[s][mt][r];
  __syncthreads();

  // combine: wave wv -> (mtile = wv&1, reg = wv>>1); lane handles one (b,f)
  const int mt_c = wv & 1, rg = wv >> 1;
  const int b_own = mt_c*16 + q*4 + rg;
  float S[4];
  #pragma unroll
  for (int s = 0; s < 4; s++) {
    const float* pp = part + ((s*2 + mt_c)*4 + rg)*512 + l*8;
    f32x4 a = *(const f32x4*)pp;
    f32x4 b = *(const f32x4*)(pp + 4);
    S[s] = ((a[0]+a[1]) + (a[2]+a[3])) + ((b[0]+b[1]) + (b[2]+b[3]));
  }
  float rr = sigmoid_f(S[0] + bR);
  float zz = sigmoid_f(S[1] + bZ);
  float nn = tanhf(S[2] + bIN + rr * (S[3] + bHN));
  float hn = (1.f - zz)*nn + zz*h_old;
  h_old = hn;
  hdst[b_own*1024 + fb*16 + c] = (unsigned short)bfbits(hn);
}

// ---------------- fused head + LN + pres + gelu (blocks 0..31, b=blk) ------
__device__ __forceinline__ void f3_stage(
    const unsigned short* __restrict__ y_bf, int t,
    const unsigned short* __restrict__ Ws_bf, const float* __restrict__ b_sout,
    const unsigned short* __restrict__ Wr_bf, const float* __restrict__ b_reward,
    const unsigned short* __restrict__ Wst_bf, const float* __restrict__ b_state,
    const float* __restrict__ g_sn, const float* __restrict__ b_sn,
    const float* __restrict__ fa_ln,
    float* __restrict__ out_r, float* __restrict__ out_s,
    unsigned short* __restrict__ xbuf_bf, float* part, int b)
{
  const int tid = threadIdx.x;
  float* yb    = part;          // 1024: y in f32
  float* spart = part + 1024;   // 512
  float* s_sh  = part + 1536;   // 256
  float* rpart = part + 1792;   // 64
  float* red1  = part + 2048;   // 512
  float* red2  = part + 2560;   // 512

  {
    unsigned uu = *(const unsigned*)(y_bf + b*1024 + tid*2);
    yb[tid*2]     = bf2f((unsigned short)(uu & 0xffffu));
    yb[tid*2 + 1] = bf2f((unsigned short)(uu >> 16));
  }
  __syncthreads();
  {  // s partials: j = tid&255, k-half = tid>>8
    const int j = tid & 255, ks = tid >> 8;
    const unsigned short* wr = Ws_bf + j*1024 + ks*512;
    const float* yp = yb + ks*512;
    float acc = 0.f;
    #pragma unroll 8
    for (int k = 0; k < 512; k += 8) acc += dot8(wr + k, yp + k);
    spart[tid] = acc;
  }
  __syncthreads();
  if (tid < 256) {
    float s = spart[tid] + spart[tid + 256] + b_sout[tid];
    out_s[((size_t)b*kT + t)*kS + tid] = s;
    s_sh[tid] = s;
  } else if (tid < 320) {
    const int idx = tid - 256, j = idx >> 3, ks = idx & 7;
    const unsigned short* wr = Wr_bf + j*1024 + ks*128;
    const float* yp = yb + ks*128;
    float acc = 0.f;
    #pragma unroll 4
    for (int k = 0; k < 128; k += 8) acc += dot8(wr + k, yp + k);
    rpart[idx] = acc;
  }
  __syncthreads();
  if (tid < 8) {
    float a = b_reward[tid];
    #pragma unroll
    for (int ks = 0; ks < 8; ks++) a += rpart[tid*8 + ks];
    out_r[((size_t)b*kT + t)*kR + tid] = tanhf(a);
  }
  if (t == kT - 1) return;   // uniform branch: last step needs no next-x
  __syncthreads();
  // u[f] = b_state[f] + W_state[f,:] @ s ; LN over 1024; x = gelu(LN + fa[t+1])
  float uv[2], s1 = 0.f, s2 = 0.f;
  #pragma unroll
  for (int jj = 0; jj < 2; jj++) {
    const int f = tid + jj*512;
    const unsigned short* wr = Wst_bf + f*256;
    float acc = b_state[f];
    #pragma unroll 8
    for (int k = 0; k < 256; k += 8) acc += dot8(wr + k, s_sh + k);
    uv[jj] = acc; s1 += acc; s2 += acc*acc;
  }
  red1[tid] = s1; red2[tid] = s2;
  __syncthreads();
  for (int off = 256; off > 0; off >>= 1) {
    if (tid < off) { red1[tid] += red1[tid + off]; red2[tid] += red2[tid + off]; }
    __syncthreads();
  }
  const float mean = red1[0] * (1.0f/kF);
  const float var  = red2[0] * (1.0f/kF) - mean*mean;
  const float inv  = rsqrtf(var + kEPS);
  #pragma unroll
  for (int jj = 0; jj < 2; jj++) {
    const int f = tid + jj*512;
    float x = (uv[jj] - mean)*inv*g_sn[f] + b_sn[f]
            + fa_ln[((size_t)(t+1)*kB + b)*kF + f];
    xbuf_bf[b*1024 + f] = (unsigned short)bfbits(gelu_f(x));
  }
}

// ---------------- persistent kernel ----------------------------------------
__global__ __launch_bounds__(BT, 2) void gru_persist(
    const float* __restrict__ gru_Wi, const float* __restrict__ gru_Wh,
    const float* __restrict__ gru_bi, const float* __restrict__ gru_bh,
    const unsigned short* __restrict__ Ws_bf, const float* __restrict__ b_sout,
    const unsigned short* __restrict__ Wr_bf, const float* __restrict__ b_reward,
    const unsigned short* __restrict__ Wst_bf, const float* __restrict__ b_state,
    const float* __restrict__ g_sn, const float* __restrict__ b_sn,
    const unsigned short* __restrict__ seq0_bf, const float* __restrict__ fa_ln,
    unsigned short* h0a, unsigned short* h0b,
    unsigned short* h1a, unsigned short* h1b,
    unsigned short* xbuf_bf,
    int* flags, int* go,
    float* __restrict__ out_r, float* __restrict__ out_s)
{
  __shared__ float part[32 * 512];   // 64 KB, aliased by all stages
  const int tid = threadIdx.x;
  const int blk = blockIdx.x;
  const int wv = tid >> 6, l = tid & 63, q = l >> 4, c = l & 15;
  const bool isL1 = (blk >= 64);
  const int fb = blk & 63;
  const int lay = isL1 ? 1 : 0;

  // ---- preamble: resident B-fragments (bf16) + gate biases ----
  short8 Bf[2][3][4];
  {
    const size_t WLL = (size_t)3 * kF * kF;
    const float* Wm[2] = { gru_Wi + lay*WLL, gru_Wh + lay*WLL };
    #pragma unroll
    for (int m = 0; m < 2; m++)
      #pragma unroll
      for (int g = 0; g < 3; g++)
        #pragma unroll
        for (int j = 0; j < 4; j++) {
          const float* p = Wm[m] + ((size_t)(g*kF + fb*16 + c))*kF + wv*128 + j*32 + q*8;
          float4 a = *(const float4*)p;
          float4 b = *(const float4*)(p + 4);
          U4S8 u;
          u.u.x = bfbits(a.x) | (bfbits(a.y) << 16);
          u.u.y = bfbits(a.z) | (bfbits(a.w) << 16);
          u.u.z = bfbits(b.x) | (bfbits(b.y) << 16);
          u.u.w = bfbits(b.z) | (bfbits(b.w) << 16);
          Bf[m][g][j] = u.s;
        }
  }
  const int f = fb*16 + c;
  const float* bi = gru_bi + lay*3*kF;
  const float* bh = gru_bh + lay*3*kF;
  const float bR  = bi[f] + bh[f];
  const float bZ  = bi[kF + f] + bh[kF + f];
  const float bIN = bi[2*kF + f];
  const float bHN = bh[2*kF + f];

  unsigned short* h0buf[2] = {h0a, h0b};
  unsigned short* h1buf[2] = {h1a, h1b};
  float h_old = 0.f;
  int gen = 1;

  // ---- history wavefront: superstage s: layer0 t=s (s<49), layer1 t=s-1 ----
  for (int s = 0; s < 50; s++) {
    if (!isL1) {
      if (s < 49)
        layer_stage(seq0_bf + (size_t)s*kB*kF, h0buf[(s+1)&1], h0buf[s&1],
                    Bf, bR, bZ, bIN, bHN, h_old, part, fb);
    } else {
      if (s >= 1)
        layer_stage(h0buf[(s-1)&1], h1buf[s&1], h1buf[(s-1)&1],
                    Bf, bR, bZ, bIN, bHN, h_old, part, fb);
    }
    grid_barrier(flags, go, gen);
  }

  // ---- future: per t: F3 (head+pres, blocks<32) -> F1 (layer0) -> F2 ----
  for (int t = 0; t < kT; t++) {
    const int tg = 48 + t;
    if (blk < kB)
      f3_stage(h1buf[tg&1], t, Ws_bf, b_sout, Wr_bf, b_reward,
               Wst_bf, b_state, g_sn, b_sn, fa_ln,
               out_r, out_s, xbuf_bf, part, blk);
    if (t == kT - 1) break;
    grid_barrier(flags, go, gen);
    if (!isL1)
      layer_stage(xbuf_bf, h0buf[tg&1], h0buf[(tg+1)&1],
                  Bf, bR, bZ, bIN, bHN, h_old, part, fb);
    grid_barrier(flags, go, gen);
    if (isL1)
      layer_stage(h0buf[(tg+1)&1], h1buf[tg&1], h1buf[(tg+1)&1],
                  Bf, bR, bZ, bIN, bHN, h_old, part, fb);
    grid_barrier(flags, go, gen);
  }
}

// ---------------- setup: convert head weights to bf16 ----------------------
__global__ __launch_bounds__(512) void convert_weights(
    const float* __restrict__ ws, unsigned short* __restrict__ o1,
    const float* __restrict__ wst, unsigned short* __restrict__ o2,
    const float* __restrict__ wr, unsigned short* __restrict__ o3)
{
  const int stride = gridDim.x * blockDim.x;
  const int i0 = blockIdx.x * blockDim.x + threadIdx.x;
  for (int i = i0; i < kS*kF; i += stride) o1[i] = (unsigned short)bfbits(ws[i]);
  for (int i = i0; i < kF*kS; i += stride) o2[i] = (unsigned short)bfbits(wst[i]);
  for (int i = i0; i < kR*kF; i += stride) o3[i] = (unsigned short)bfbits(wr[i]);
}

// ---------------- encoder: fa_ln[t][b][f] = LN(future_a@Wa^T+ba)*g+b (f32) -
__global__ __launch_bounds__(256) void encode_fa_kernel(
    const float* __restrict__ future_a,
    const float* __restrict__ W_action, const float* __restrict__ b_action,
    const float* __restrict__ g_an, const float* __restrict__ b_an,
    float* __restrict__ fa_ln)
{
  __shared__ __align__(16) float arow[kA];
  __shared__ float red1[256], red2[256];
  const int bid = blockIdx.x;
  const int b = bid & (kB - 1);
  const int t = bid >> 5;
  const int tid = threadIdx.x;
  if (tid < kA) arow[tid] = future_a[((size_t)b*kT + t)*kA + tid];
  __syncthreads();
  float v[4]; float s1 = 0.f, s2 = 0.f;
  #pragma unroll
  for (int j = 0; j < 4; j++) {
    const int ff = tid + j*256;
    const float* wr = W_action + (size_t)ff*kA;
    float acc = b_action[ff];
    for (int k = 0; k < kA; k += 4) {
      float4 w  = *(const float4*)(wr + k);
      float4 xv = *(const float4*)(arow + k);
      acc += xv.x*w.x + xv.y*w.y + xv.z*w.z + xv.w*w.w;
    }
    v[j] = acc; s1 += acc; s2 += acc*acc;
  }
  red1[tid] = s1; red2[tid] = s2;
  __syncthreads();
  for (int off = 128; off > 0; off >>= 1) {
    if (tid < off) { red1[tid] += red1[tid+off]; red2[tid] += red2[tid+off]; }
    __syncthreads();
  }
  const float m = red1[0] * (1.0f/kF);
  const float va = red2[0] * (1.0f/kF) - m*m;
  const float inv = rsqrtf(va + kEPS);
  #pragma unroll
  for (int j = 0; j < 4; j++) {
    const int ff = tid + j*256;
    fa_ln[((size_t)t*kB + b)*kF + ff] = (v[j] - m)*inv*g_an[ff] + b_an[ff];
  }
}

// ---------------- encoder: seq0_bf = bf16(gelu(LN_s + LN_a)) ---------------
__global__ __launch_bounds__(256) void encode_seq0_kernel(
    const float* __restrict__ history_s, const float* __restrict__ history_a,
    const float* __restrict__ present_s,
    const float* __restrict__ W_state, const float* __restrict__ b_state,
    const float* __restrict__ g_sn, const float* __restrict__ b_sn,
    const float* __restrict__ W_action, const float* __restrict__ b_action,
    const float* __restrict__ g_an, const float* __restrict__ b_an,
    const float* __restrict__ fa_ln, unsigned short* __restrict__ seq0_bf)
{
  __shared__ __align__(16) float srow[kS];
  __shared__ __align__(16) float arow[kA];
  __shared__ float red1[256], red2[256];
  const int bid = blockIdx.x;
  const int b = bid & (kB - 1);
  const int t = bid >> 5;                 // 0..48
  const int tid = threadIdx.x;
  const bool hist = (t < kH);
  const float* sp = hist ? (history_s + ((size_t)b*kH + t)*kS)
                         : (present_s + (size_t)b*kS);
  srow[tid] = sp[tid];
  if (hist && tid < kA) arow[tid] = history_a[((size_t)b*kH + t)*kA + tid];
  __syncthreads();

  float u[4]; float s1 = 0.f, s2 = 0.f;
  #pragma unroll
  for (int j = 0; j < 4; j++) {
    const int ff = tid + j*256;
    const float* wr = W_state + (size_t)ff*kS;
    float acc = b_state[ff];
    for (int k = 0; k < kS; k += 4) {
      float4 w  = *(const float4*)(wr + k);
      float4 xv = *(const float4*)(srow + k);
      acc += xv.x*w.x + xv.y*w.y + xv.z*w.z + xv.w*w.w;
    }
    u[j] = acc; s1 += acc; s2 += acc*acc;
  }
  red1[tid] = s1; red2[tid] = s2;
  __syncthreads();
  for (int off = 128; off > 0; off >>= 1) {
    if (tid < off) { red1[tid] += red1[tid+off]; red2[tid] += red2[tid+off]; }
    __syncthreads();
  }
  const float mu = red1[0] * (1.0f/kF);
  const float vu = red2[0] * (1.0f/kF) - mu*mu;
  const float iu = rsqrtf(vu + kEPS);
  __syncthreads();

  if (hist) {
    float v[4]; s1 = 0.f; s2 = 0.f;
    #pragma unroll
    for (int j = 0; j < 4; j++) {
      const int ff = tid + j*256;
      const float* wr = W_action + (size_t)ff*kA;
      float acc = b_action[ff];
      for (int k = 0; k < kA; k += 4) {
        float4 w  = *(const float4*)(wr + k);
        float4 xv = *(const float4*)(arow + k);
        acc += xv.x*w.x + xv.y*w.y + xv.z*w.z + xv.w*w.w;
      }
      v[j] = acc; s1 += acc; s2 += acc*acc;
    }
    red1[tid] = s1; red2[tid] = s2;
    __syncthreads();
    for (int off = 128; off > 0; off >>= 1) {
      if (tid < off) { red1[tid] += red1[tid+off]; red2[tid] += red2[tid+off]; }
      __syncthreads();
    }
    const float mv = red1[0] * (1.0f/kF);
    const float vv = red2[0] * (1.0f/kF) - mv*mv;
    const float iv = rsqrtf(vv + kEPS);
    #pragma unroll
    for (int j = 0; j < 4; j++) {
      const int ff = tid + j*256;
      const float un = (u[j] - mu)*iu*g_sn[ff] + b_sn[ff];
      const float vn = (v[j] - mv)*iv*g_an[ff] + b_an[ff];
      seq0_bf[((size_t)t*kB + b)*kF + ff] = (unsigned short)bfbits(gelu_f(un + vn));
    }
  } else {
    #pragma unroll
    for (int j = 0; j < 4; j++) {
      const int ff = tid + j*256;
      const float un = (u[j] - mu)*iu*g_sn[ff] + b_sn[ff];
      seq0_bf[((size_t)t*kB + b)*kF + ff] =
          (unsigned short)bfbits(gelu_f(un + fa_ln[(size_t)b*kF + ff]));
    }
  }
}

// ---------------- host launcher -------------------------------------------
extern "C" void kernel_launch(void* const* d_in, const int* in_sizes, int n_in,
                              void* d_out, int out_size, void* d_ws, size_t ws_size,
                              hipStream_t stream) {
  (void)in_sizes; (void)n_in; (void)out_size;
  const float* history_s = (const float*)d_in[0];
  const float* history_a = (const float*)d_in[1];
  const float* present_s = (const float*)d_in[2];
  /* d_in[3] future_s: unused by the reference forward */
  const float* future_a  = (const float*)d_in[4];
  const float* W_state   = (const float*)d_in[5];
  const float* b_state   = (const float*)d_in[6];
  const float* g_sn      = (const float*)d_in[7];
  const float* b_sn      = (const float*)d_in[8];
  const float* W_action  = (const float*)d_in[9];
  const float* b_action  = (const float*)d_in[10];
  const float* g_an      = (const float*)d_in[11];
  const float* b_an      = (const float*)d_in[12];
  const float* gru_Wi    = (const float*)d_in[13];
  const float* gru_Wh    = (const float*)d_in[14];
  const float* gru_bi    = (const float*)d_in[15];
  const float* gru_bh    = (const float*)d_in[16];
  const float* W_reward  = (const float*)d_in[17];
  const float* b_reward  = (const float*)d_in[18];
  const float* W_sout    = (const float*)d_in[19];
  const float* b_sout    = (const float*)d_in[20];

  // workspace layout (bytes, all 16-aligned)
  char* ws = (char*)d_ws;
  unsigned short* seq0_bf = (unsigned short*)(ws + 0);            // 3,211,264
  float*          fa_ln   = (float*)(ws + 3211264);               // 3,145,728
  unsigned short* Ws_bf   = (unsigned short*)(ws + 6356992);      // 524,288
  unsigned short* Wst_bf  = (unsigned short*)(ws + 6881280);      // 524,288
  unsigned short* Wr_bf   = (unsigned short*)(ws + 7405568);      // 16,384
  unsigned short* h0a     = (unsigned short*)(ws + 7421952);      // 65,536
  unsigned short* h0b     = (unsigned short*)(ws + 7487488);      // 65,536
  unsigned short* h1a     = (unsigned short*)(ws + 7553024);      // 65,536
  unsigned short* h1b     = (unsigned short*)(ws + 7618560);      // 65,536
  unsigned short* xbuf_bf = (unsigned short*)(ws + 7684096);      // 65,536
  int*            flags   = (int*)(ws + 7749632);                 // 512
  int*            go      = (int*)(ws + 7750144);                 // 4
  const size_t need = 7750148;
  if (ws_size < need) return;

  // zero hidden-state buffers + barrier state (ws is re-poisoned each launch)
  hipMemsetAsync((void*)h0a, 0, 7750148 - 7421952, stream);

  float* out_r = (float*)d_out;                          // [B][T][R]
  float* out_s = out_r + (size_t)kB*kT*kR;               // [B][T][S]

  hipLaunchKernelGGL(convert_weights, dim3(512), dim3(512), 0, stream,
                     W_sout, Ws_bf, W_state, Wst_bf, W_reward, Wr_bf);
  hipLaunchKernelGGL(encode_fa_kernel, dim3(kT*kB), dim3(256), 0, stream,
                     future_a, W_action, b_action, g_an, b_an, fa_ln);
  hipLaunchKernelGGL(encode_seq0_kernel, dim3(kSEQ*kB), dim3(256), 0, stream,
                     history_s, history_a, present_s,
                     W_state, b_state, g_sn, b_sn,
                     W_action, b_action, g_an, b_an, fa_ln, seq0_bf);
  hipLaunchKernelGGL(gru_persist, dim3(G), dim3(BT), 0, stream,
                     gru_Wi, gru_Wh, gru_bi, gru_bh,
                     Ws_bf, b_sout, Wr_bf, b_reward, Wst_bf, b_state,
                     g_sn, b_sn, seq0_bf, fa_ln,
                     h0a, h0b, h1a, h1b, xbuf_bf, flags, go,
                     out_r, out_s);
}